// Round 13
// baseline (33.424 us; speedup 1.0000x reference)
//
#include <hip/hip_runtime.h>
#include <math.h>

#define DIM 128
#define P_POS 3
#define N_NEG 63
#define SCALE 16.0f

typedef float floatx2 __attribute__((ext_vector_type(2)));

#if defined(__has_builtin)
#if __has_builtin(__builtin_elementwise_fma)
#define HAVE_EFMA 1
#endif
#endif

__device__ __forceinline__ floatx2 pkfma(floatx2 a, floatx2 b, floatx2 c) {
#ifdef HAVE_EFMA
    return __builtin_elementwise_fma(a, b, c);
#else
    floatx2 r;
    r.x = fmaf(a.x, b.x, c.x);
    r.y = fmaf(a.y, b.y, c.y);
    return r;
#endif
}

__device__ __forceinline__ float wave_reduce_sum(float v) {
#pragma unroll
    for (int off = 32; off > 0; off >>= 1) v += __shfl_xor(v, off, 64);
    return v;
}
// four interleaved wave reductions (chains overlap in the LDS-swizzle pipe)
__device__ __forceinline__ void wave_reduce4(float& a, float& b, float& c, float& d) {
#pragma unroll
    for (int off = 32; off > 0; off >>= 1) {
        a += __shfl_xor(a, off, 64);
        b += __shfl_xor(b, off, 64);
        c += __shfl_xor(c, off, 64);
        d += __shfl_xor(d, off, 64);
    }
}
__device__ __forceinline__ float g8_reduce(float v) {
#pragma unroll
    for (int off = 4; off > 0; off >>= 1) v += __shfl_xor(v, off, 64);
    return v;
}
__device__ __forceinline__ float g32_reduce(float v) {
#pragma unroll
    for (int off = 16; off > 0; off >>= 1) v += __shfl_xor(v, off, 64);
    return v;
}

// Normalize each ids_fut row, scale by 16, pack to fp8 e4m3 (round-3 proven).
__global__ __launch_bounds__(256) void prep_fp8_kernel(const float* __restrict__ fut,
                                                       unsigned* __restrict__ futq,
                                                       int nrows) {
    int half = threadIdx.x >> 5;
    int l = threadIdx.x & 31;
    int row = blockIdx.x * 8 + half;
    if (row >= nrows) return;
    float4 x = *reinterpret_cast<const float4*>(fut + (size_t)row * DIM + l * 4);
    float ss = x.x * x.x;
    ss = fmaf(x.y, x.y, ss);
    ss = fmaf(x.z, x.z, ss);
    ss = fmaf(x.w, x.w, ss);
    ss = g32_reduce(ss);
    float r = (ss > 0.f) ? rsqrtf(ss) * SCALE : 0.f;
    int w = __builtin_amdgcn_cvt_pk_fp8_f32(x.x * r, x.y * r, 0, false);
    w = __builtin_amdgcn_cvt_pk_fp8_f32(x.z * r, x.w * r, w, true);
    futq[(size_t)row * 32 + l] = (unsigned)w;
}

__device__ __forceinline__ void dq8(uint4 v, const floatx2* av, floatx2& x, floatx2& y,
                                    floatx2& z, floatx2& w) {
    x = pkfma(__builtin_amdgcn_cvt_pk_f32_fp8(v.x, false), av[0], x);
    y = pkfma(__builtin_amdgcn_cvt_pk_f32_fp8(v.x, true), av[1], y);
    z = pkfma(__builtin_amdgcn_cvt_pk_f32_fp8(v.y, false), av[2], z);
    w = pkfma(__builtin_amdgcn_cvt_pk_f32_fp8(v.y, true), av[3], w);
    x = pkfma(__builtin_amdgcn_cvt_pk_f32_fp8(v.z, false), av[4], x);
    y = pkfma(__builtin_amdgcn_cvt_pk_f32_fp8(v.z, true), av[5], y);
    z = pkfma(__builtin_amdgcn_cvt_pk_f32_fp8(v.w, false), av[6], z);
    w = pkfma(__builtin_amdgcn_cvt_pk_f32_fp8(v.w, true), av[7], w);
}

// TWO anchors per wave; 8 groups x 8 lanes; uint4 gathers; both bursts issued
// before either dequant (intra-wave ILP: chain B computes while chain A waits).
// No barrier, no LDS: each wave writes partials[m0..m1] as one float2.
__global__ __launch_bounds__(256) void idloss_fp8d_kernel(
    const float* __restrict__ hist, const int* __restrict__ anchor_idx,
    const int* __restrict__ pos_idx, const int* __restrict__ neg_idx,
    const uint4* __restrict__ futq, float* __restrict__ partials) {
    const int wave = threadIdx.x >> 6;
    const int lane = threadIdx.x & 63;
    const int m0 = __builtin_amdgcn_readfirstlane((blockIdx.x * 4 + wave) * 2);
    const int m1 = m0 + 1;
    const int g = lane >> 3;   // group 0..7
    const int t = lane & 7;    // 16 B chunk of the 128-B row

    // ---- index loads for both anchors (issued back-to-back)
    int nidx0 = (lane < N_NEG) ? neg_idx[m0 * N_NEG + lane] : 0;
    int nidx1 = (lane < N_NEG) ? neg_idx[m1 * N_NEG + lane] : 0;
    const int aidx0 = anchor_idx[m0];
    const int aidx1 = anchor_idx[m1];
    const int p00 = pos_idx[m0 * P_POS + 0];
    const int p01 = pos_idx[m0 * P_POS + 1];
    const int p02 = pos_idx[m0 * P_POS + 2];
    const int p10 = pos_idx[m1 * P_POS + 0];
    const int p11 = pos_idx[m1 * P_POS + 1];
    const int p12 = pos_idx[m1 * P_POS + 2];
    int pidx0 = (g == 1) ? p01 : (g == 2) ? p02 : p00;
    int pidx1 = (g == 1) ? p11 : (g == 2) ? p12 : p10;

    // ---- anchor rows (elements [16t,16t+16), replicated across groups)
    const float4* apA =
        reinterpret_cast<const float4*>(hist + (size_t)aidx0 * DIM + t * 16);
    const float4* apB =
        reinterpret_cast<const float4*>(hist + (size_t)aidx1 * DIM + t * 16);
    float4 A[4], B[4];
#pragma unroll
    for (int i = 0; i < 4; ++i) A[i] = apA[i];
#pragma unroll
    for (int i = 0; i < 4; ++i) B[i] = apB[i];

    float ssA = 0.f, ssB = 0.f;
#pragma unroll
    for (int i = 0; i < 4; ++i) {
        ssA = fmaf(A[i].x, A[i].x, ssA); ssA = fmaf(A[i].y, A[i].y, ssA);
        ssA = fmaf(A[i].z, A[i].z, ssA); ssA = fmaf(A[i].w, A[i].w, ssA);
        ssB = fmaf(B[i].x, B[i].x, ssB); ssB = fmaf(B[i].y, B[i].y, ssB);
        ssB = fmaf(B[i].z, B[i].z, ssB); ssB = fmaf(B[i].w, B[i].w, ssB);
    }
    ssA = g8_reduce(ssA);
    ssB = g8_reduce(ssB);
    float rnaA = (ssA > 0.f) ? rsqrtf(ssA) * (1.0f / SCALE) : 0.f;
    float rnaB = (ssB > 0.f) ? rsqrtf(ssB) * (1.0f / SCALE) : 0.f;
    floatx2 avA[8], avB[8];
#pragma unroll
    for (int i = 0; i < 4; ++i) {
        avA[2 * i].x = A[i].x * rnaA; avA[2 * i].y = A[i].y * rnaA;
        avA[2 * i + 1].x = A[i].z * rnaA; avA[2 * i + 1].y = A[i].w * rnaA;
        avB[2 * i].x = B[i].x * rnaB; avB[2 * i].y = B[i].y * rnaB;
        avB[2 * i + 1].x = B[i].z * rnaB; avB[2 * i + 1].y = B[i].w * rnaB;
    }

    // ---- broadcast neg indices for both anchors
    int jsA[8], jsB[8];
#pragma unroll
    for (int k = 0; k < 8; ++k) jsA[k] = __shfl(nidx0, 8 * k + g, 64);
#pragma unroll
    for (int k = 0; k < 8; ++k) jsB[k] = __shfl(nidx1, 8 * k + g, 64);

    // ---- both gather bursts in flight together
    uint4 vpA = futq[(size_t)pidx0 * 8 + t];
    uint4 vpB = futq[(size_t)pidx1 * 8 + t];
    if (g >= P_POS) {
        vpA.x = vpA.y = vpA.z = vpA.w = 0u;
        vpB.x = vpB.y = vpB.z = vpB.w = 0u;
    }
    uint4 vsA[8], vsB[8];
#pragma unroll
    for (int k = 0; k < 8; ++k) {
        vsA[k] = futq[(size_t)jsA[k] * 8 + t];
        if (8 * k + g >= N_NEG) { vsA[k].x = vsA[k].y = vsA[k].z = vsA[k].w = 0u; }
    }
#pragma unroll
    for (int k = 0; k < 8; ++k) {
        vsB[k] = futq[(size_t)jsB[k] * 8 + t];
        if (8 * k + g >= N_NEG) { vsB[k].x = vsB[k].y = vsB[k].z = vsB[k].w = 0u; }
    }

    // ---- dequant anchor 0 (overlaps anchor-1 gather latency), then anchor 1
    floatx2 nA0 = {0.f, 0.f}, nA1 = {0.f, 0.f}, nA2 = {0.f, 0.f}, nA3 = {0.f, 0.f};
#pragma unroll
    for (int k = 0; k < 8; ++k) dq8(vsA[k], avA, nA0, nA1, nA2, nA3);
    floatx2 pA0 = {0.f, 0.f}, pA1 = {0.f, 0.f}, pA2 = {0.f, 0.f}, pA3 = {0.f, 0.f};
    dq8(vpA, avA, pA0, pA1, pA2, pA3);

    floatx2 nB0 = {0.f, 0.f}, nB1 = {0.f, 0.f}, nB2 = {0.f, 0.f}, nB3 = {0.f, 0.f};
#pragma unroll
    for (int k = 0; k < 8; ++k) dq8(vsB[k], avB, nB0, nB1, nB2, nB3);
    floatx2 pB0 = {0.f, 0.f}, pB1 = {0.f, 0.f}, pB2 = {0.f, 0.f}, pB3 = {0.f, 0.f};
    dq8(vpB, avB, pB0, pB1, pB2, pB3);

    floatx2 nsA = (nA0 + nA1) + (nA2 + nA3);
    floatx2 psA = (pA0 + pA1) + (pA2 + pA3);
    floatx2 nsB = (nB0 + nB1) + (nB2 + nB3);
    floatx2 psB = (pB0 + pB1) + (pB2 + pB3);
    float accnA = nsA.x + nsA.y;
    float accpA = psA.x + psA.y;
    float accnB = nsB.x + nsB.y;
    float accpB = psB.x + psB.y;
    wave_reduce4(accnA, accpA, accnB, accpB);

    if (lane == 0) {
        float spA = accpA + (float)P_POS;
        float snA = accnA + (float)N_NEG;
        float spB = accpB + (float)P_POS;
        float snB = accnB + (float)N_NEG;
        float2 r;
        r.x = -logf(spA / (spA + snA));
        r.y = -logf(spB / (spB + snB));
        *reinterpret_cast<float2*>(partials + m0) = r;
    }
}

// Single-block 1024-thread reduce: each thread owns one float4.
__global__ __launch_bounds__(1024) void reduce1024_kernel(
    const float* __restrict__ partials, float* __restrict__ out, int n4) {
    __shared__ float smem[16];
    const int tid = threadIdx.x;
    const int lane = tid & 63;
    const int wid = tid >> 6;
    float acc = 0.f;
    for (int i = tid; i < n4; i += 1024) {
        float4 v = reinterpret_cast<const float4*>(partials)[i];
        acc += (v.x + v.y) + (v.z + v.w);
    }
    acc = wave_reduce_sum(acc);
    if (lane == 0) smem[wid] = acc;
    __syncthreads();
    if (tid == 0) {
        float s = 0.f;
#pragma unroll
        for (int i = 0; i < 16; ++i) s += smem[i];
        out[0] = s;
    }
}

extern "C" void kernel_launch(void* const* d_in, const int* in_sizes, int n_in,
                              void* d_out, int out_size, void* d_ws, size_t ws_size,
                              hipStream_t stream) {
    const float* fut  = (const float*)d_in[0];
    const float* hist = (const float*)d_in[1];
    const int* anchor_idx = (const int*)d_in[2];
    const int* pos_idx    = (const int*)d_in[3];
    const int* neg_idx    = (const int*)d_in[4];

    int N = in_sizes[0] / DIM;   // 66560
    int M = in_sizes[2];         // 16384
    int main_blocks = M / 8;     // 2048 (2 anchors per wave, 4 waves per block)

    size_t futq_bytes = (size_t)N * 32 * sizeof(unsigned);   // fp8 table, 128 B/row
    unsigned* futq = (unsigned*)d_ws;
    float* partials = (float*)((char*)d_ws + futq_bytes);    // M floats

    int prep_blocks = (N + 7) / 8;
    prep_fp8_kernel<<<prep_blocks, 256, 0, stream>>>(fut, futq, N);
    idloss_fp8d_kernel<<<main_blocks, 256, 0, stream>>>(hist, anchor_idx, pos_idx,
                                                        neg_idx, (const uint4*)futq,
                                                        partials);
    reduce1024_kernel<<<1, 1024, 0, stream>>>(partials, (float*)d_out, M / 4);
}

// Round 14
// 31.215 us; speedup vs baseline: 1.0708x; 1.0708x over previous
//
#include <hip/hip_runtime.h>
#include <math.h>

#define DIM 128
#define P_POS 3
#define N_NEG 63
#define SCALE 16.0f

typedef float floatx2 __attribute__((ext_vector_type(2)));

#if defined(__has_builtin)
#if __has_builtin(__builtin_elementwise_fma)
#define HAVE_EFMA 1
#endif
#endif

__device__ __forceinline__ floatx2 pkfma(floatx2 a, floatx2 b, floatx2 c) {
#ifdef HAVE_EFMA
    return __builtin_elementwise_fma(a, b, c);
#else
    floatx2 r;
    r.x = fmaf(a.x, b.x, c.x);
    r.y = fmaf(a.y, b.y, c.y);
    return r;
#endif
}

__device__ __forceinline__ float wave_reduce_sum(float v) {
#pragma unroll
    for (int off = 32; off > 0; off >>= 1) v += __shfl_xor(v, off, 64);
    return v;
}
__device__ __forceinline__ float g8_reduce(float v) {
#pragma unroll
    for (int off = 4; off > 0; off >>= 1) v += __shfl_xor(v, off, 64);
    return v;
}
__device__ __forceinline__ float g32_reduce(float v) {
#pragma unroll
    for (int off = 16; off > 0; off >>= 1) v += __shfl_xor(v, off, 64);
    return v;
}

// Normalize each ids_fut row, scale by 16, pack to fp8 e4m3 (round-3 proven).
__global__ __launch_bounds__(256) void prep_fp8_kernel(const float* __restrict__ fut,
                                                       unsigned* __restrict__ futq,
                                                       int nrows) {
    int half = threadIdx.x >> 5;
    int l = threadIdx.x & 31;
    int row = blockIdx.x * 8 + half;
    if (row >= nrows) return;
    float4 x = *reinterpret_cast<const float4*>(fut + (size_t)row * DIM + l * 4);
    float ss = x.x * x.x;
    ss = fmaf(x.y, x.y, ss);
    ss = fmaf(x.z, x.z, ss);
    ss = fmaf(x.w, x.w, ss);
    ss = g32_reduce(ss);
    float r = (ss > 0.f) ? rsqrtf(ss) * SCALE : 0.f;
    int w = __builtin_amdgcn_cvt_pk_fp8_f32(x.x * r, x.y * r, 0, false);
    w = __builtin_amdgcn_cvt_pk_fp8_f32(x.z * r, x.w * r, w, true);
    futq[(size_t)row * 32 + l] = (unsigned)w;
}

// One wave per anchor; 8 groups x 8 lanes; uint4 (16 B/lane) gathers.
// Round-12 best-measured configuration (31.0 us total). Main kernel is at the
// empirical random-gather floor (~16.3 us across 6 structural variants).
__global__ __launch_bounds__(256) void idloss_fp8w_kernel(
    const float* __restrict__ hist, const int* __restrict__ anchor_idx,
    const int* __restrict__ pos_idx, const int* __restrict__ neg_idx,
    const uint4* __restrict__ futq, float* __restrict__ partials) {
    __shared__ float smem[4];
    const int wave = threadIdx.x >> 6;
    const int lane = threadIdx.x & 63;
    const int m = __builtin_amdgcn_readfirstlane(blockIdx.x * 4 + wave);
    const int g = lane >> 3;   // group 0..7 (one sample row per group per gather)
    const int t = lane & 7;    // lane-in-group: 16 B of the 128-B row

    // per-lane coalesced neg-index load (broadcast via shfl below)
    int nidx = (lane < N_NEG) ? neg_idx[m * N_NEG + lane] : 0;

    // wave-uniform scalar loads
    const int aidx = anchor_idx[m];
    const int p0 = pos_idx[m * P_POS + 0];
    const int p1 = pos_idx[m * P_POS + 1];
    const int p2 = pos_idx[m * P_POS + 2];
    int pidx = (g == 1) ? p1 : (g == 2) ? p2 : p0;

    // anchor elements [16t, 16t+16), replicated across the 8 groups
    const float4* ap =
        reinterpret_cast<const float4*>(hist + (size_t)aidx * DIM + t * 16);
    float4 A0 = ap[0], A1 = ap[1], A2 = ap[2], A3 = ap[3];
    float ss = A0.x * A0.x;
    ss = fmaf(A0.y, A0.y, ss); ss = fmaf(A0.z, A0.z, ss); ss = fmaf(A0.w, A0.w, ss);
    ss = fmaf(A1.x, A1.x, ss); ss = fmaf(A1.y, A1.y, ss);
    ss = fmaf(A1.z, A1.z, ss); ss = fmaf(A1.w, A1.w, ss);
    ss = fmaf(A2.x, A2.x, ss); ss = fmaf(A2.y, A2.y, ss);
    ss = fmaf(A2.z, A2.z, ss); ss = fmaf(A2.w, A2.w, ss);
    ss = fmaf(A3.x, A3.x, ss); ss = fmaf(A3.y, A3.y, ss);
    ss = fmaf(A3.z, A3.z, ss); ss = fmaf(A3.w, A3.w, ss);
    ss = g8_reduce(ss);
    float rna = (ss > 0.f) ? rsqrtf(ss) * (1.0f / SCALE) : 0.f;
    floatx2 av0, av1, av2, av3, av4, av5, av6, av7;
    av0.x = A0.x * rna; av0.y = A0.y * rna;
    av1.x = A0.z * rna; av1.y = A0.w * rna;
    av2.x = A1.x * rna; av2.y = A1.y * rna;
    av3.x = A1.z * rna; av3.y = A1.w * rna;
    av4.x = A2.x * rna; av4.y = A2.y * rna;
    av5.x = A2.z * rna; av5.y = A2.w * rna;
    av6.x = A3.x * rna; av6.y = A3.y * rna;
    av7.x = A3.z * rna; av7.y = A3.w * rna;

    // broadcast neg indices in-register: gather k, group g handles slot 8k+g
    int js[8];
#pragma unroll
    for (int k = 0; k < 8; ++k) js[k] = __shfl(nidx, 8 * k + g, 64);

    // burst-issue: 1 pos gather (groups 0-2) + 8 neg gathers (slot 63 masked)
    uint4 vp = futq[(size_t)pidx * 8 + t];
    if (g >= P_POS) { vp.x = vp.y = vp.z = vp.w = 0u; }
    uint4 vs[8];
#pragma unroll
    for (int k = 0; k < 8; ++k) {
        vs[k] = futq[(size_t)js[k] * 8 + t];
        if (8 * k + g >= N_NEG) { vs[k].x = vs[k].y = vs[k].z = vs[k].w = 0u; }
    }

    // packed dots; 4 interleaved accumulators
    floatx2 n0 = {0.f, 0.f}, n1 = {0.f, 0.f}, n2 = {0.f, 0.f}, n3 = {0.f, 0.f};
#pragma unroll
    for (int k = 0; k < 8; ++k) {
        uint4 v = vs[k];
        n0 = pkfma(__builtin_amdgcn_cvt_pk_f32_fp8(v.x, false), av0, n0);
        n1 = pkfma(__builtin_amdgcn_cvt_pk_f32_fp8(v.x, true), av1, n1);
        n2 = pkfma(__builtin_amdgcn_cvt_pk_f32_fp8(v.y, false), av2, n2);
        n3 = pkfma(__builtin_amdgcn_cvt_pk_f32_fp8(v.y, true), av3, n3);
        n0 = pkfma(__builtin_amdgcn_cvt_pk_f32_fp8(v.z, false), av4, n0);
        n1 = pkfma(__builtin_amdgcn_cvt_pk_f32_fp8(v.z, true), av5, n1);
        n2 = pkfma(__builtin_amdgcn_cvt_pk_f32_fp8(v.w, false), av6, n2);
        n3 = pkfma(__builtin_amdgcn_cvt_pk_f32_fp8(v.w, true), av7, n3);
    }
    floatx2 pa = {0.f, 0.f}, pb = {0.f, 0.f};
    pa = pkfma(__builtin_amdgcn_cvt_pk_f32_fp8(vp.x, false), av0, pa);
    pb = pkfma(__builtin_amdgcn_cvt_pk_f32_fp8(vp.x, true), av1, pb);
    pa = pkfma(__builtin_amdgcn_cvt_pk_f32_fp8(vp.y, false), av2, pa);
    pb = pkfma(__builtin_amdgcn_cvt_pk_f32_fp8(vp.y, true), av3, pb);
    pa = pkfma(__builtin_amdgcn_cvt_pk_f32_fp8(vp.z, false), av4, pa);
    pb = pkfma(__builtin_amdgcn_cvt_pk_f32_fp8(vp.z, true), av5, pb);
    pa = pkfma(__builtin_amdgcn_cvt_pk_f32_fp8(vp.w, false), av6, pa);
    pb = pkfma(__builtin_amdgcn_cvt_pk_f32_fp8(vp.w, true), av7, pb);

    floatx2 ns = (n0 + n1) + (n2 + n3);
    floatx2 ps = pa + pb;
    float accn = wave_reduce_sum(ns.x + ns.y);
    float accp = wave_reduce_sum(ps.x + ps.y);

    if (lane == 0) {
        float sp = accp + (float)P_POS;
        float sn = accn + (float)N_NEG;
        smem[wave] = -logf(sp / (sp + sn));
    }
    __syncthreads();
    if (threadIdx.x == 0)
        partials[blockIdx.x] = smem[0] + smem[1] + smem[2] + smem[3];
}

// Single-block 1024-thread reduce: each thread owns one float4.
__global__ __launch_bounds__(1024) void reduce1024_kernel(
    const float* __restrict__ partials, float* __restrict__ out, int n4) {
    __shared__ float smem[16];
    const int tid = threadIdx.x;
    const int lane = tid & 63;
    const int wid = tid >> 6;
    float acc = 0.f;
    for (int i = tid; i < n4; i += 1024) {
        float4 v = reinterpret_cast<const float4*>(partials)[i];
        acc += (v.x + v.y) + (v.z + v.w);
    }
    acc = wave_reduce_sum(acc);
    if (lane == 0) smem[wid] = acc;
    __syncthreads();
    if (tid == 0) {
        float s = 0.f;
#pragma unroll
        for (int i = 0; i < 16; ++i) s += smem[i];
        out[0] = s;
    }
}

extern "C" void kernel_launch(void* const* d_in, const int* in_sizes, int n_in,
                              void* d_out, int out_size, void* d_ws, size_t ws_size,
                              hipStream_t stream) {
    const float* fut  = (const float*)d_in[0];
    const float* hist = (const float*)d_in[1];
    const int* anchor_idx = (const int*)d_in[2];
    const int* pos_idx    = (const int*)d_in[3];
    const int* neg_idx    = (const int*)d_in[4];

    int N = in_sizes[0] / DIM;   // 66560
    int M = in_sizes[2];         // 16384
    int main_blocks = M / 4;     // 4096

    size_t futq_bytes = (size_t)N * 32 * sizeof(unsigned);   // fp8 table, 128 B/row
    unsigned* futq = (unsigned*)d_ws;
    float* partials = (float*)((char*)d_ws + futq_bytes);

    int prep_blocks = (N + 7) / 8;
    prep_fp8_kernel<<<prep_blocks, 256, 0, stream>>>(fut, futq, N);
    idloss_fp8w_kernel<<<main_blocks, 256, 0, stream>>>(hist, anchor_idx, pos_idx,
                                                        neg_idx, (const uint4*)futq,
                                                        partials);
    reduce1024_kernel<<<1, 1024, 0, stream>>>(partials, (float*)d_out,
                                              main_blocks / 4);
}